// Round 6
// baseline (416.158 us; speedup 1.0000x reference)
//
#include <hip/hip_runtime.h>

// Stencil gather: out[b,j,k,{center,up,right,down,left}], edge-replicated.
// B=16, H=1024, W=1024, f32. 64 MiB read + 320 MiB write -> ~64-85 us floor.
// Graph dur = ~210 us harness poison-fill (per timed iteration, fixed) +
// stencil.
//
// History: R0 (1 row/block, LDS transpose, nt stores) 367.6 graph / ~157
// stencil. R1 persistent 4-wave bands 378.7. R2 wave-autonomous 389.1.
// R5 nt->plain A/B: 374.7 -> nt theory DEAD (plain neutral/slightly worse).
// Every structure pins at ~2.5 TB/s effective, and the stencil dispatch has
// NEVER appeared in the top-5 counter table (hidden under the ~210 us fills).
//
// R6 = DIAGNOSTIC ROUND, not an optimization. Exact R0 body run reps=2
// (runtime trip count + asm memory clobber so the compiler can neither CSE
// the pass-2 loads nor dead-store-eliminate pass-1 stores; pass 2 rewrites
// identical values -> output unchanged, absmax 0.0). Duration ~2x157 =
// ~314 us > every fill -> the stencil surfaces in top-5 WITH its counters.
//
// Pre-committed decision rule on the stencil row (per-pass = value/2):
//   WRITE_SIZE >> 655e3 KB            -> write amplification (RMW) = theory A
//   FETCH_SIZE ~393e3 KB              -> LLC not absorbing row re-reads
//   hbm_gbps >= ~5500                 -> BW-saturated, chase phantom traffic
//   hbm_gbps ~2500-3000               -> true underachievement, chase
//                                        issue-rate/latency next round
//   also read: OccupancyPercent, VALUBusy, SQ_LDS_BANK_CONFLICT (expect 0).
// Graph dur expected ~525 us this round — paid for measurement.

typedef float f4 __attribute__((ext_vector_type(4)));

__global__ __launch_bounds__(256) void stencil5_kernel(
    const float* __restrict__ in, float* __restrict__ out, int reps) {
    constexpr int W = 1024;
    constexpr int H = 1024;

    __shared__ float lds[256 * 20];   // 20 KiB -> 8 blocks/CU

    const int i   = threadIdx.x;
    const int row = blockIdx.x;        // global row in [0, B*H)
    const int k0  = i << 2;            // starting column (multiple of 4)
    const int j   = row & (H - 1);     // row within image

    const long base = ((long)row << 10);
    const float* prow = in + base + k0;

    for (int p = 0; p < reps; ++p) {
        // Opaque barrier: forces genuine reloads and keeps both passes'
        // stores live (no CSE/DSE across passes).
        asm volatile("" ::: "memory");

        // Center (16B-aligned).
        const float4 c = *(const float4*)prow;

        // Up / down rows, replicating the center row at borders.
        const float* uptr = prow - ((j > 0)     ? W : 0);
        const float* dptr = prow + ((j < H - 1) ? W : 0);
        const float4 u = *(const float4*)uptr;
        const float4 d = *(const float4*)dptr;

        // Left neighbor of pixel0 / right neighbor of pixel3.
        float lx = prow[-(k0 > 0 ? 1 : 0)];
        lx = (k0 > 0) ? lx : c.x;
        float rw = prow[(k0 + 4 < W) ? 4 : 3];
        rw = (k0 + 4 < W) ? rw : c.w;

        // Per-pixel output (pixel-major, channel-minor), 20 floats:
        // [c.x,u.x,c.y,d.x,lx | c.y,u.y,c.z,d.y,c.x | c.z,u.z,c.w,d.z,c.y |
        //  c.w,u.w,rw,d.w,c.z]
        float4* l = (float4*)(lds + i * 20);
        l[0] = make_float4(c.x, u.x, c.y, d.x);
        l[1] = make_float4(lx,  c.y, u.y, c.z);
        l[2] = make_float4(d.y, c.x, c.z, u.z);
        l[3] = make_float4(c.w, d.z, c.y, c.w);
        l[4] = make_float4(u.w, rw,  d.w, c.z);

        __syncthreads();

        // Coalesced streaming store of the block's 20 KiB (1280 float4s),
        // nontemporal (R0's best-measured flavor).
        const f4* ls = (const f4*)lds;
        f4* o = (f4*)(out + base * 5);
        #pragma unroll
        for (int r = 0; r < 5; ++r) {
            __builtin_nontemporal_store(ls[i + 256 * r], o + i + 256 * r);
        }

        __syncthreads();   // protect LDS before next pass rewrites it
    }
}

extern "C" void kernel_launch(void* const* d_in, const int* in_sizes, int n_in,
                              void* d_out, int out_size, void* d_ws, size_t ws_size,
                              hipStream_t stream) {
    const float* in = (const float*)d_in[0];
    float* out = (float*)d_out;

    const int n = in_sizes[0];       // B*H*W = 16 * 1024 * 1024
    const int blocks = n >> 10;      // one block per 1024-pixel row = 16384

    stencil5_kernel<<<blocks, 256, 0, stream>>>(in, out, /*reps=*/2);
}

// Round 7
// 367.301 us; speedup vs baseline: 1.1330x; 1.1330x over previous
//
#include <hip/hip_runtime.h>

// Stencil gather: out[b,j,k,{center,up,right,down,left}], edge-replicated.
// B=16, H=1024, W=1024, f32. Mandatory traffic: 67 MB read + 335 MB write.
//
// FINAL (R7 = revert of the R6 reps=2 diagnostic to the best kernel, R0).
//
// Session conclusion (R6 diagnostic evidence):
//  - Marginal cost of a full extra stencil pass in-dispatch = +48.6 us for
//    335 MB of stores = ~6.9 TB/s — at/above the 6.3-6.4 TB/s achievable
//    HBM ceiling. The kernel's store stream is at the memory roofline.
//  - reps=2 never appeared above the 208 us fills -> single pass < ~104 us;
//    combined with the marginal measurement, stencil ~50-60 us.
//  - Graph dur (~367 us) is dominated by ~310-320 us of fixed harness reset
//    (one 1.25 GiB poison fill @ 210 us + dozens of tiny memset/restore
//    dispatches + launch gaps), not by this kernel.
//  - Retro-explains R1 (persistent bands, +11 us), R2 (wave-autonomous,
//    +21 us), R5 (plain stores, +7 us): restructures of an already
//    roofline-bound ~55 us kernel; no headroom existed.
//
// Mapping: 1 block (256 threads) = 1 image row = 1024 pixels = 20 KiB output.
//  Phase 1: thread i computes pixels [4i,4i+4) -> 5 float4s -> LDS at 80B*i
//           (bank quad 20i mod 32: conflict-free).
//  Phase 2: barrier; thread i stores LDS float4 [i+256r] -> out float4
//           [block_base + i + 256r], r=0..4. Fully coalesced nontemporal
//           (output never re-read; best measured flavor: nt 367.6 vs
//           plain 374.7).

typedef float f4 __attribute__((ext_vector_type(4)));

__global__ __launch_bounds__(256) void stencil5_kernel(
    const float* __restrict__ in, float* __restrict__ out) {
    constexpr int W = 1024;
    constexpr int H = 1024;

    __shared__ float lds[256 * 20];   // 20 KiB -> 8 blocks/CU

    const int i   = threadIdx.x;
    const int row = blockIdx.x;        // global row in [0, B*H)
    const int k0  = i << 2;            // starting column (multiple of 4)
    const int j   = row & (H - 1);     // row within image

    const long base = ((long)row << 10);
    const float* prow = in + base + k0;

    // Center (16B-aligned).
    const float4 c = *(const float4*)prow;

    // Up / down rows, replicating the center row at borders (wave-uniform).
    const float* uptr = prow - ((j > 0)     ? W : 0);
    const float* dptr = prow + ((j < H - 1) ? W : 0);
    const float4 u = *(const float4*)uptr;
    const float4 d = *(const float4*)dptr;

    // Left neighbor of pixel0 / right neighbor of pixel3 (clamped address,
    // then per-lane select to center at the image border).
    float lx = prow[-(k0 > 0 ? 1 : 0)];
    lx = (k0 > 0) ? lx : c.x;
    float rw = prow[(k0 + 4 < W) ? 4 : 3];
    rw = (k0 + 4 < W) ? rw : c.w;

    // Per-pixel output (pixel-major, channel-minor), 20 floats:
    // [c.x,u.x,c.y,d.x,lx | c.y,u.y,c.z,d.y,c.x | c.z,u.z,c.w,d.z,c.y |
    //  c.w,u.w,rw,d.w,c.z]
    float4* l = (float4*)(lds + i * 20);
    l[0] = make_float4(c.x, u.x, c.y, d.x);
    l[1] = make_float4(lx,  c.y, u.y, c.z);
    l[2] = make_float4(d.y, c.x, c.z, u.z);
    l[3] = make_float4(c.w, d.z, c.y, c.w);
    l[4] = make_float4(u.w, rw,  d.w, c.z);

    __syncthreads();

    // Coalesced streaming store of the block's 20 KiB (1280 float4s).
    const f4* ls = (const f4*)lds;
    f4* o = (f4*)(out + base * 5);
    #pragma unroll
    for (int r = 0; r < 5; ++r) {
        __builtin_nontemporal_store(ls[i + 256 * r], o + i + 256 * r);
    }
}

extern "C" void kernel_launch(void* const* d_in, const int* in_sizes, int n_in,
                              void* d_out, int out_size, void* d_ws, size_t ws_size,
                              hipStream_t stream) {
    const float* in = (const float*)d_in[0];
    float* out = (float*)d_out;

    const int n = in_sizes[0];       // B*H*W = 16 * 1024 * 1024
    const int blocks = n >> 10;      // one block per 1024-pixel row = 16384

    stencil5_kernel<<<blocks, 256, 0, stream>>>(in, out);
}